// Round 1
// baseline (3299.062 us; speedup 1.0000x reference)
//
#include <hip/hip_runtime.h>
#include <math.h>

#define CDIM 256
#define SDIM 4096
#define NBATCH 4

// ---------------------------------------------------------------------------
// Kernel 1: fused 1x1-conv projections.
//   theta[n][c][s] = Wt @ x + bt        (c,s layout, same as input x)
//   phi  [n][c][s] = Wp @ x + bp
//   g_t  [n][s][c] = (Wg @ x + bg)^T    (s,c layout for coalesced PV reads)
// GEMM per (batch, proj): M=256 (c_out), N=4096 (s), K=256 (c_in).
// grid (S/64, C/64, NBATCH*3), block 256, 64x64 tile, 4x4 per thread.
// ---------------------------------------------------------------------------
__global__ __launch_bounds__(256)
void proj_kernel(const float* __restrict__ x,
                 const float* __restrict__ Wt, const float* __restrict__ bt,
                 const float* __restrict__ Wp, const float* __restrict__ bp,
                 const float* __restrict__ Wg, const float* __restrict__ bg,
                 float* __restrict__ theta, float* __restrict__ phi,
                 float* __restrict__ g_t)
{
    const int p = blockIdx.z % 3;           // 0: theta, 1: phi, 2: g
    const int n = blockIdx.z / 3;
    const float* W    = (p == 0) ? Wt : (p == 1) ? Wp : Wg;
    const float* bias = (p == 0) ? bt : (p == 1) ? bp : bg;
    const float* xb = x + (size_t)n * CDIM * SDIM;

    const int s0 = blockIdx.x * 64;
    const int m0 = blockIdx.y * 64;

    __shared__ float As[16][68];   // W tile, [k][m]
    __shared__ float Bs[16][68];   // x tile, [k][s]

    const int t  = threadIdx.x;
    const int tx = t & 15;         // s-frag /4
    const int ty = t >> 4;         // m-frag /4

    float acc[4][4] = {};

    for (int k0 = 0; k0 < CDIM; k0 += 16) {
        {
            const int ka = t & 15, ma = t >> 4;
            #pragma unroll
            for (int i = 0; i < 4; i++)
                As[ka][ma + 16 * i] = W[(size_t)(m0 + ma + 16 * i) * CDIM + k0 + ka];
            const int sb = t & 63, cb = t >> 6;
            #pragma unroll
            for (int i = 0; i < 4; i++)
                Bs[cb + 4 * i][sb] = xb[(size_t)(k0 + cb + 4 * i) * SDIM + s0 + sb];
        }
        __syncthreads();
        #pragma unroll
        for (int kk = 0; kk < 16; kk++) {
            const float4 a = *(const float4*)&As[kk][ty * 4];
            const float4 b = *(const float4*)&Bs[kk][tx * 4];
            acc[0][0] += a.x * b.x; acc[0][1] += a.x * b.y; acc[0][2] += a.x * b.z; acc[0][3] += a.x * b.w;
            acc[1][0] += a.y * b.x; acc[1][1] += a.y * b.y; acc[1][2] += a.y * b.z; acc[1][3] += a.y * b.w;
            acc[2][0] += a.z * b.x; acc[2][1] += a.z * b.y; acc[2][2] += a.z * b.z; acc[2][3] += a.z * b.w;
            acc[3][0] += a.w * b.x; acc[3][1] += a.w * b.y; acc[3][2] += a.w * b.z; acc[3][3] += a.w * b.w;
        }
        __syncthreads();
    }

    if (p < 2) {
        float* out = ((p == 0) ? theta : phi) + (size_t)n * CDIM * SDIM;
        #pragma unroll
        for (int i = 0; i < 4; i++) {
            const int m = m0 + ty * 4 + i;
            const float bv = bias[m];
            float4 v = make_float4(acc[i][0] + bv, acc[i][1] + bv,
                                   acc[i][2] + bv, acc[i][3] + bv);
            *(float4*)&out[(size_t)m * SDIM + s0 + tx * 4] = v;
        }
    } else {
        float* out = g_t + (size_t)n * SDIM * CDIM;
        float bv[4];
        #pragma unroll
        for (int i = 0; i < 4; i++) bv[i] = bias[m0 + ty * 4 + i];
        #pragma unroll
        for (int j = 0; j < 4; j++) {
            float4 v = make_float4(acc[0][j] + bv[0], acc[1][j] + bv[1],
                                   acc[2][j] + bv[2], acc[3][j] + bv[3]);
            *(float4*)&out[(size_t)(s0 + tx * 4 + j) * CDIM + m0 + ty * 4] = v;
        }
    }
}

// ---------------------------------------------------------------------------
// Kernel 2: fused flash-style attention (no scale, softmax over keys).
//   y[n][q][c] = sum_k softmax_k(theta[:,q].phi[:,k]) * g_t[k][c]
// Block: 32 queries, chunks of 128 keys over all 4096. block 256 threads.
//   S-GEMM mapping: tys=t>>5 (q/4), txs=t&31 (k/4), 4x4 frag.
//   PV  mapping:    qg=t>>4 (q/2),  cg=t&15  (c/16), 2x16 O frag.
// LDS ~59 KB -> 2 blocks/CU.
// ---------------------------------------------------------------------------
__global__ __launch_bounds__(256)
void attn_kernel(const float* __restrict__ theta,
                 const float* __restrict__ phi,
                 const float* __restrict__ g_t,
                 float* __restrict__ y)
{
    const int n  = blockIdx.y;
    const int q0 = blockIdx.x * 32;
    const float* th = theta + (size_t)n * CDIM * SDIM;
    const float* ph = phi   + (size_t)n * CDIM * SDIM;
    const float* gt = g_t   + (size_t)n * SDIM * CDIM;

    __shared__ float As[32][36];    // theta chunk [c][q]
    __shared__ float Bs[32][132];   // phi chunk   [c][k]
    __shared__ float Ps[32][132];   // probs       [q][k]
    __shared__ float Gs[16][260];   // g chunk     [k][c]
    __shared__ float m_s[32], l_s[32], alpha_s[32];

    const int t   = threadIdx.x;
    const int txs = t & 31;   // S: k/4
    const int tys = t >> 5;   // S: q/4
    const int cg  = t & 15;   // PV: c/16
    const int qg  = t >> 4;   // PV: q/2

    if (t < 32) { m_s[t] = -INFINITY; l_s[t] = 0.0f; }
    float O[2][16];
    #pragma unroll
    for (int i = 0; i < 2; i++)
        #pragma unroll
        for (int c = 0; c < 16; c++) O[i][c] = 0.0f;
    __syncthreads();

    for (int k0 = 0; k0 < SDIM; k0 += 128) {
        // ---- S = theta^T @ phi  (32q x 128k, K=256) ----
        float sacc[4][4] = {};
        for (int c0 = 0; c0 < CDIM; c0 += 32) {
            {
                const int qa = t & 31, ca = t >> 5;     // ca 0..7
                #pragma unroll
                for (int i = 0; i < 4; i++)
                    As[ca + 8 * i][qa] = th[(size_t)(c0 + ca + 8 * i) * SDIM + q0 + qa];
                const int kb = t & 127, cb = t >> 7;    // cb 0..1
                #pragma unroll
                for (int i = 0; i < 16; i++)
                    Bs[cb + 2 * i][kb] = ph[(size_t)(c0 + cb + 2 * i) * SDIM + k0 + kb];
            }
            __syncthreads();
            #pragma unroll
            for (int kk = 0; kk < 32; kk++) {
                const float4 a = *(const float4*)&As[kk][tys * 4];
                const float4 b = *(const float4*)&Bs[kk][txs * 4];
                sacc[0][0] += a.x * b.x; sacc[0][1] += a.x * b.y; sacc[0][2] += a.x * b.z; sacc[0][3] += a.x * b.w;
                sacc[1][0] += a.y * b.x; sacc[1][1] += a.y * b.y; sacc[1][2] += a.y * b.z; sacc[1][3] += a.y * b.w;
                sacc[2][0] += a.z * b.x; sacc[2][1] += a.z * b.y; sacc[2][2] += a.z * b.z; sacc[2][3] += a.z * b.w;
                sacc[3][0] += a.w * b.x; sacc[3][1] += a.w * b.y; sacc[3][2] += a.w * b.z; sacc[3][3] += a.w * b.w;
            }
            __syncthreads();
        }

        // ---- online softmax over this 128-key chunk ----
        float mnew[4], al[4], psum[4];
        #pragma unroll
        for (int i = 0; i < 4; i++) {
            float mx = fmaxf(fmaxf(sacc[i][0], sacc[i][1]), fmaxf(sacc[i][2], sacc[i][3]));
            #pragma unroll
            for (int off = 16; off >= 1; off >>= 1)
                mx = fmaxf(mx, __shfl_xor(mx, off));
            const int q = tys * 4 + i;
            const float mo = m_s[q];                 // same value across the 32 row lanes
            mnew[i] = fmaxf(mo, mx);
            al[i]   = __expf(mo - mnew[i]);
            float sum = 0.0f;
            #pragma unroll
            for (int j = 0; j < 4; j++) {
                const float pv = __expf(sacc[i][j] - mnew[i]);
                sacc[i][j] = pv;
                sum += pv;
            }
            #pragma unroll
            for (int off = 16; off >= 1; off >>= 1)
                sum += __shfl_xor(sum, off);
            psum[i] = sum;
        }
        #pragma unroll
        for (int i = 0; i < 4; i++)
            *(float4*)&Ps[tys * 4 + i][txs * 4] =
                make_float4(sacc[i][0], sacc[i][1], sacc[i][2], sacc[i][3]);
        if (txs == 0) {
            #pragma unroll
            for (int i = 0; i < 4; i++) {
                const int q = tys * 4 + i;
                m_s[q] = mnew[i];
                l_s[q] = l_s[q] * al[i] + psum[i];
                alpha_s[q] = al[i];
            }
        }
        __syncthreads();

        // ---- rescale O, then O += P @ G over this chunk ----
        const float a0 = alpha_s[qg * 2 + 0];
        const float a1 = alpha_s[qg * 2 + 1];
        #pragma unroll
        for (int c = 0; c < 16; c++) { O[0][c] *= a0; O[1][c] *= a1; }

        for (int ks = 0; ks < 128; ks += 16) {
            __syncthreads();   // protect Gs from previous sub-chunk readers
            #pragma unroll
            for (int kk = 0; kk < 16; kk++)
                Gs[kk][t] = gt[(size_t)(k0 + ks + kk) * CDIM + t];
            __syncthreads();
            #pragma unroll
            for (int kk = 0; kk < 16; kk++) {
                const float p0 = Ps[qg * 2 + 0][ks + kk];
                const float p1 = Ps[qg * 2 + 1][ks + kk];
                #pragma unroll
                for (int cv = 0; cv < 4; cv++) {
                    const float4 gv = *(const float4*)&Gs[kk][cg * 16 + cv * 4];
                    O[0][cv * 4 + 0] += p0 * gv.x; O[0][cv * 4 + 1] += p0 * gv.y;
                    O[0][cv * 4 + 2] += p0 * gv.z; O[0][cv * 4 + 3] += p0 * gv.w;
                    O[1][cv * 4 + 0] += p1 * gv.x; O[1][cv * 4 + 1] += p1 * gv.y;
                    O[1][cv * 4 + 2] += p1 * gv.z; O[1][cv * 4 + 3] += p1 * gv.w;
                }
            }
        }
        __syncthreads();   // all PV reads of Ps done before next chunk overwrites
    }

    const float inv0 = 1.0f / l_s[qg * 2 + 0];
    const float inv1 = 1.0f / l_s[qg * 2 + 1];
    float* yb = y + (size_t)n * SDIM * CDIM;
    #pragma unroll
    for (int i = 0; i < 2; i++) {
        const float inv = i ? inv1 : inv0;
        #pragma unroll
        for (int cv = 0; cv < 4; cv++) {
            float4 v = make_float4(O[i][cv * 4 + 0] * inv, O[i][cv * 4 + 1] * inv,
                                   O[i][cv * 4 + 2] * inv, O[i][cv * 4 + 3] * inv);
            *(float4*)&yb[(size_t)(q0 + qg * 2 + i) * CDIM + cg * 16 + cv * 4] = v;
        }
    }
}

// ---------------------------------------------------------------------------
// Kernel 3: output projection + residual.
//   out[n][c][s] = x[n][c][s] + bo[c] + sum_cin Wo[c][cin] * y[n][s][cin]
// y is (s,c) so the B-tile is transposed through LDS.
// ---------------------------------------------------------------------------
__global__ __launch_bounds__(256)
void outproj_kernel(const float* __restrict__ y,
                    const float* __restrict__ Wo,
                    const float* __restrict__ bo,
                    const float* __restrict__ x,
                    float* __restrict__ out)
{
    const int n = blockIdx.z;
    const int s0 = blockIdx.x * 64;
    const int m0 = blockIdx.y * 64;
    const float* yb = y + (size_t)n * SDIM * CDIM;

    __shared__ float As[16][68];   // Wo tile [k][m]
    __shared__ float Bs[16][68];   // y tile  [k][s]

    const int t = threadIdx.x, tx = t & 15, ty = t >> 4;
    float acc[4][4] = {};

    for (int k0 = 0; k0 < CDIM; k0 += 16) {
        {
            const int ka = t & 15, ma = t >> 4;
            #pragma unroll
            for (int i = 0; i < 4; i++)
                As[ka][ma + 16 * i] = Wo[(size_t)(m0 + ma + 16 * i) * CDIM + k0 + ka];
            const int kb = t & 15, sb = t >> 4;
            #pragma unroll
            for (int i = 0; i < 4; i++)
                Bs[kb][sb + 16 * i] = yb[(size_t)(s0 + sb + 16 * i) * CDIM + k0 + kb];
        }
        __syncthreads();
        #pragma unroll
        for (int kk = 0; kk < 16; kk++) {
            const float4 a = *(const float4*)&As[kk][ty * 4];
            const float4 b = *(const float4*)&Bs[kk][tx * 4];
            acc[0][0] += a.x * b.x; acc[0][1] += a.x * b.y; acc[0][2] += a.x * b.z; acc[0][3] += a.x * b.w;
            acc[1][0] += a.y * b.x; acc[1][1] += a.y * b.y; acc[1][2] += a.y * b.z; acc[1][3] += a.y * b.w;
            acc[2][0] += a.z * b.x; acc[2][1] += a.z * b.y; acc[2][2] += a.z * b.z; acc[2][3] += a.z * b.w;
            acc[3][0] += a.w * b.x; acc[3][1] += a.w * b.y; acc[3][2] += a.w * b.z; acc[3][3] += a.w * b.w;
        }
        __syncthreads();
    }

    const float* xb = x + (size_t)n * CDIM * SDIM;
    #pragma unroll
    for (int i = 0; i < 4; i++) {
        const int m = m0 + ty * 4 + i;
        const float bv = bo[m];
        const float4 xv = *(const float4*)&xb[(size_t)m * SDIM + s0 + tx * 4];
        float4 v = make_float4(acc[i][0] + bv + xv.x, acc[i][1] + bv + xv.y,
                               acc[i][2] + bv + xv.z, acc[i][3] + bv + xv.w);
        *(float4*)&out[((size_t)n * CDIM + m) * SDIM + s0 + tx * 4] = v;
    }
}

// ---------------------------------------------------------------------------
extern "C" void kernel_launch(void* const* d_in, const int* in_sizes, int n_in,
                              void* d_out, int out_size, void* d_ws, size_t ws_size,
                              hipStream_t stream)
{
    const float* x  = (const float*)d_in[0];
    const float* Wg = (const float*)d_in[1];
    const float* bg = (const float*)d_in[2];
    const float* Wt = (const float*)d_in[3];
    const float* bt = (const float*)d_in[4];
    const float* Wp = (const float*)d_in[5];
    const float* bp = (const float*)d_in[6];
    const float* Wo = (const float*)d_in[7];
    const float* bo = (const float*)d_in[8];

    const size_t buf = (size_t)NBATCH * CDIM * SDIM;   // 4 Mi floats each
    float* ws    = (float*)d_ws;
    float* theta = ws;
    float* phi   = ws + buf;
    float* g_t   = ws + 2 * buf;
    float* y     = ws + 3 * buf;
    float* out   = (float*)d_out;

    proj_kernel<<<dim3(SDIM / 64, CDIM / 64, NBATCH * 3), 256, 0, stream>>>(
        x, Wt, bt, Wp, bp, Wg, bg, theta, phi, g_t);
    attn_kernel<<<dim3(SDIM / 32, NBATCH), 256, 0, stream>>>(theta, phi, g_t, y);
    outproj_kernel<<<dim3(SDIM / 64, CDIM / 64, NBATCH), 256, 0, stream>>>(
        y, Wo, bo, x, out);
}

// Round 2
// 583.292 us; speedup vs baseline: 5.6559x; 5.6559x over previous
//
#include <hip/hip_runtime.h>
#include <math.h>

#define CDIM 256
#define SDIM 4096
#define NBATCH 4

typedef _Float16 f16;
typedef _Float16 f16x4 __attribute__((ext_vector_type(4)));
typedef _Float16 f16x8 __attribute__((ext_vector_type(8)));
typedef float    f32x16 __attribute__((ext_vector_type(16)));

// ---------------------------------------------------------------------------
// Kernel 1: fused 1x1-conv projections (fp32 compute, f16 outputs).
//   theta_t[n][s][c] = (Wt @ x + bt)^T   (s,c) f16  -> A-frags contiguous
//   phi_t  [n][s][c] = (Wp @ x + bp)^T   (s,c) f16  -> B-frag rows contiguous
//   g      [n][c][s] =  Wg @ x + bg      (c,s) f16  -> G A-frag rows contiguous
// ---------------------------------------------------------------------------
__global__ __launch_bounds__(256)
void proj_kernel(const float* __restrict__ x,
                 const float* __restrict__ Wt, const float* __restrict__ bt,
                 const float* __restrict__ Wp, const float* __restrict__ bp,
                 const float* __restrict__ Wg, const float* __restrict__ bg,
                 f16* __restrict__ theta_t, f16* __restrict__ phi_t,
                 f16* __restrict__ g_out)
{
    const int p = blockIdx.z % 3;           // 0: theta, 1: phi, 2: g
    const int n = blockIdx.z / 3;
    const float* W    = (p == 0) ? Wt : (p == 1) ? Wp : Wg;
    const float* bias = (p == 0) ? bt : (p == 1) ? bp : bg;
    const float* xb = x + (size_t)n * CDIM * SDIM;

    const int s0 = blockIdx.x * 64;
    const int m0 = blockIdx.y * 64;

    __shared__ float As[16][68];   // W tile, [k][m]
    __shared__ float Bs[16][68];   // x tile, [k][s]

    const int t  = threadIdx.x;
    const int tx = t & 15;         // s-frag /4
    const int ty = t >> 4;         // m-frag /4

    float acc[4][4] = {};

    for (int k0 = 0; k0 < CDIM; k0 += 16) {
        {
            const int ka = t & 15, ma = t >> 4;
            #pragma unroll
            for (int i = 0; i < 4; i++)
                As[ka][ma + 16 * i] = W[(size_t)(m0 + ma + 16 * i) * CDIM + k0 + ka];
            const int sb = t & 63, cb = t >> 6;
            #pragma unroll
            for (int i = 0; i < 4; i++)
                Bs[cb + 4 * i][sb] = xb[(size_t)(k0 + cb + 4 * i) * SDIM + s0 + sb];
        }
        __syncthreads();
        #pragma unroll
        for (int kk = 0; kk < 16; kk++) {
            const float4 a = *(const float4*)&As[kk][ty * 4];
            const float4 b = *(const float4*)&Bs[kk][tx * 4];
            acc[0][0] += a.x * b.x; acc[0][1] += a.x * b.y; acc[0][2] += a.x * b.z; acc[0][3] += a.x * b.w;
            acc[1][0] += a.y * b.x; acc[1][1] += a.y * b.y; acc[1][2] += a.y * b.z; acc[1][3] += a.y * b.w;
            acc[2][0] += a.z * b.x; acc[2][1] += a.z * b.y; acc[2][2] += a.z * b.z; acc[2][3] += a.z * b.w;
            acc[3][0] += a.w * b.x; acc[3][1] += a.w * b.y; acc[3][2] += a.w * b.z; acc[3][3] += a.w * b.w;
        }
        __syncthreads();
    }

    if (p < 2) {
        // transposed (s, c) f16 output
        f16* out = ((p == 0) ? theta_t : phi_t) + (size_t)n * SDIM * CDIM;
        float bv[4];
        #pragma unroll
        for (int i = 0; i < 4; i++) bv[i] = bias[m0 + ty * 4 + i];
        #pragma unroll
        for (int j = 0; j < 4; j++) {
            const int s = s0 + tx * 4 + j;
            f16x4 v;
            v[0] = (f16)(acc[0][j] + bv[0]);
            v[1] = (f16)(acc[1][j] + bv[1]);
            v[2] = (f16)(acc[2][j] + bv[2]);
            v[3] = (f16)(acc[3][j] + bv[3]);
            *(f16x4*)&out[(size_t)s * CDIM + m0 + ty * 4] = v;
        }
    } else {
        // (c, s) f16 output
        f16* out = g_out + (size_t)n * CDIM * SDIM;
        #pragma unroll
        for (int i = 0; i < 4; i++) {
            const int m = m0 + ty * 4 + i;
            const float bv = bias[m];
            f16x4 v;
            v[0] = (f16)(acc[i][0] + bv);
            v[1] = (f16)(acc[i][1] + bv);
            v[2] = (f16)(acc[i][2] + bv);
            v[3] = (f16)(acc[i][3] + bv);
            *(f16x4*)&out[(size_t)m * SDIM + s0 + tx * 4] = v;
        }
    }
}

// ---------------------------------------------------------------------------
// Kernel 2: MFMA flash attention.
// Block = 64 queries, 4 waves in 2x2: wm = query-half (32 q), wn = key/chan split.
// K-chunks of 64 keys. Per chunk:
//   phase 1: stage phi[64k x 256c] (f16, XOR-swizzled 16B chunks) into bufA
//   phase 2: S = theta^T phi via mfma_32x32x16_f16 (theta A-frags preloaded
//            in 64 VGPRs); raw S (fp32) -> Ps_raw
//   phase 3: stage G[64k x 256c] into bufA + cooperative online softmax
//            (4 threads per row); P (f16) -> Ps_h in B-frag layout
//   phase 4: O^T = G^T P^T accumulation via mfma (O^T: M=chan, N=query)
// MFMA frag model: A[m][k]: m=lane%32, k=8*(lane/32)+i ; B[k][n]: n=lane%32,
// k=8*(lane/32)+i ; C/D: col=lane&31, row=(reg&3)+8*(reg>>2)+4*(lane>>5).
// ---------------------------------------------------------------------------
__global__ __launch_bounds__(256)
void attn_kernel(const f16* __restrict__ theta,
                 const f16* __restrict__ phi,
                 const f16* __restrict__ g,
                 float* __restrict__ y)
{
    const int bid = blockIdx.x;
    const int n   = bid >> 6;           // batch slow-varying
    const int q0  = (bid & 63) * 64;

    __shared__ f16x8 bufA[2048];        // 32 KB: phi_s then Gs (per chunk)
    __shared__ float Ps_raw[64][68];    // raw logits, fp32
    __shared__ f16x8 Ps_h[512];         // P in B-frag layout [kchunk8][q64]
    __shared__ float m_s[64], l_s[64], alpha_s[64];

    const int t  = threadIdx.x;
    const int w  = t >> 6;
    const int l  = t & 63;
    const int wm = w & 1;               // query 32-half
    const int wn = w >> 1;              // key tile (S) / channel 128-half (PV)
    const int ln = l & 31;
    const int hi = l >> 5;

    const f16* thb = theta + (size_t)n * SDIM * CDIM;
    const f16* phb = phi   + (size_t)n * SDIM * CDIM;
    const f16* gb  = g     + (size_t)n * CDIM * SDIM;

    // theta A-fragments for this wave's 32 queries (held all kernel: 64 VGPRs)
    f16x8 aF[16];
    {
        const f16* ap = thb + (size_t)(q0 + 32 * wm + ln) * CDIM + hi * 8;
        #pragma unroll
        for (int j = 0; j < 16; ++j)
            aF[j] = *(const f16x8*)(ap + 16 * j);
    }

    f32x16 O[4];
    #pragma unroll
    for (int mt = 0; mt < 4; ++mt)
        #pragma unroll
        for (int r = 0; r < 16; ++r) O[mt][r] = 0.0f;

    if (t < 64) { m_s[t] = -INFINITY; l_s[t] = 0.0f; }

    for (int k0 = 0; k0 < SDIM; k0 += 64) {
        __syncthreads();                       // prior PV done; bufA/Ps_raw free
        // ---- stage phi chunk: chunks = (key, chanGrp), slot = grp ^ (key&31)
        #pragma unroll
        for (int it = 0; it < 8; ++it) {
            const int id  = it * 256 + t;
            const int key = id >> 5;
            const int grp = id & 31;
            f16x8 v = *(const f16x8*)(phb + (size_t)(k0 + key) * CDIM + grp * 8);
            bufA[key * 32 + (grp ^ (key & 31))] = v;
        }
        __syncthreads();

        // ---- S = theta^T phi (this wave: 32 q x 32 k, K=256)
        {
            f32x16 sC;
            #pragma unroll
            for (int r = 0; r < 16; ++r) sC[r] = 0.0f;
            const int key = 32 * wn + ln;
            #pragma unroll
            for (int j = 0; j < 16; ++j) {
                const int grp = 2 * j + hi;
                f16x8 b = bufA[key * 32 + (grp ^ (key & 31))];
                sC = __builtin_amdgcn_mfma_f32_32x32x16_f16(aF[j], b, sC, 0, 0, 0);
            }
            #pragma unroll
            for (int r = 0; r < 16; ++r) {
                const int row = (r & 3) + 8 * (r >> 2) + 4 * hi;
                Ps_raw[32 * wm + row][32 * wn + ln] = sC[r];
            }
        }
        __syncthreads();

        // ---- stage G (bufA now free) + cooperative online softmax
        #pragma unroll
        for (int it = 0; it < 8; ++it) {
            const int chan = it * 32 + (t >> 3);
            const int kg   = t & 7;
            f16x8 v = *(const f16x8*)(gb + (size_t)chan * SDIM + k0 + kg * 8);
            bufA[kg * 256 + (chan ^ (kg << 2))] = v;
        }
        {
            const int q  = t >> 2;
            const int qt = t & 3;
            float arr[16];
            *(float4*)&arr[0]  = *(const float4*)&Ps_raw[q][qt * 16 + 0];
            *(float4*)&arr[4]  = *(const float4*)&Ps_raw[q][qt * 16 + 4];
            *(float4*)&arr[8]  = *(const float4*)&Ps_raw[q][qt * 16 + 8];
            *(float4*)&arr[12] = *(const float4*)&Ps_raw[q][qt * 16 + 12];
            float mx = arr[0];
            #pragma unroll
            for (int i = 1; i < 16; ++i) mx = fmaxf(mx, arr[i]);
            mx = fmaxf(mx, __shfl_xor(mx, 1));
            mx = fmaxf(mx, __shfl_xor(mx, 2));
            const float mo = m_s[q];
            const float mn = fmaxf(mo, mx);
            const float al = __expf(mo - mn);
            float sum = 0.0f;
            #pragma unroll
            for (int i = 0; i < 16; ++i) {
                arr[i] = __expf(arr[i] - mn);
                sum += arr[i];
            }
            sum += __shfl_xor(sum, 1);
            sum += __shfl_xor(sum, 2);
            if (qt == 0) {
                m_s[q] = mn;
                alpha_s[q] = al;
                l_s[q] = l_s[q] * al + sum;
            }
            f16x8 h0, h1;
            #pragma unroll
            for (int i = 0; i < 8; ++i) { h0[i] = (f16)arr[i]; h1[i] = (f16)arr[8 + i]; }
            Ps_h[(2 * qt + 0) * 64 + q] = h0;
            Ps_h[(2 * qt + 1) * 64 + q] = h1;
        }
        __syncthreads();

        // ---- PV: O^T += G^T P^T (this wave: 128 chans x 32 q, K=64 keys)
        {
            const float al = alpha_s[32 * wm + ln];
            if (__any(al != 1.0f)) {
                #pragma unroll
                for (int mt = 0; mt < 4; ++mt)
                    #pragma unroll
                    for (int r = 0; r < 16; ++r) O[mt][r] *= al;
            }
            #pragma unroll
            for (int st = 0; st < 4; ++st) {
                const int kc = 2 * st + hi;
                f16x8 pB = Ps_h[kc * 64 + 32 * wm + ln];
                #pragma unroll
                for (int mt = 0; mt < 4; ++mt) {
                    const int chan = 128 * wn + 32 * mt + ln;
                    f16x8 gA = bufA[kc * 256 + (chan ^ (kc << 2))];
                    O[mt] = __builtin_amdgcn_mfma_f32_32x32x16_f16(gA, pB, O[mt], 0, 0, 0);
                }
            }
        }
    }

    // ---- epilogue: normalize by l, write y (c, s) fp32
    {
        const float linv = 1.0f / l_s[32 * wm + ln];
        float* yb = y + (size_t)n * CDIM * SDIM;
        #pragma unroll
        for (int mt = 0; mt < 4; ++mt) {
            #pragma unroll
            for (int r = 0; r < 16; ++r) {
                const int row  = (r & 3) + 8 * (r >> 2) + 4 * hi;
                const int chan = 128 * wn + 32 * mt + row;
                yb[(size_t)chan * SDIM + q0 + 32 * wm + ln] = O[mt][r] * linv;
            }
        }
    }
}

// ---------------------------------------------------------------------------
// Kernel 3: output projection + residual.  y is (c, s) fp32 now, so the
// B staging is identical to proj_kernel's x staging.
//   out[n][c][s] = x[n][c][s] + bo[c] + sum_ci Wo[c][ci] * y[n][ci][s]
// ---------------------------------------------------------------------------
__global__ __launch_bounds__(256)
void outproj_kernel(const float* __restrict__ y,
                    const float* __restrict__ Wo,
                    const float* __restrict__ bo,
                    const float* __restrict__ x,
                    float* __restrict__ out)
{
    const int n  = blockIdx.z;
    const int s0 = blockIdx.x * 64;
    const int m0 = blockIdx.y * 64;
    const float* yb = y + (size_t)n * CDIM * SDIM;

    __shared__ float As[16][68];   // Wo tile [k][m]
    __shared__ float Bs[16][68];   // y tile  [k][s]

    const int t = threadIdx.x, tx = t & 15, ty = t >> 4;
    float acc[4][4] = {};

    for (int k0 = 0; k0 < CDIM; k0 += 16) {
        {
            const int ka = t & 15, ma = t >> 4;
            #pragma unroll
            for (int i = 0; i < 4; i++)
                As[ka][ma + 16 * i] = Wo[(size_t)(m0 + ma + 16 * i) * CDIM + k0 + ka];
            const int sb = t & 63, cb = t >> 6;
            #pragma unroll
            for (int i = 0; i < 4; i++)
                Bs[cb + 4 * i][sb] = yb[(size_t)(k0 + cb + 4 * i) * SDIM + s0 + sb];
        }
        __syncthreads();
        #pragma unroll
        for (int kk = 0; kk < 16; kk++) {
            const float4 a = *(const float4*)&As[kk][ty * 4];
            const float4 b = *(const float4*)&Bs[kk][tx * 4];
            acc[0][0] += a.x * b.x; acc[0][1] += a.x * b.y; acc[0][2] += a.x * b.z; acc[0][3] += a.x * b.w;
            acc[1][0] += a.y * b.x; acc[1][1] += a.y * b.y; acc[1][2] += a.y * b.z; acc[1][3] += a.y * b.w;
            acc[2][0] += a.z * b.x; acc[2][1] += a.z * b.y; acc[2][2] += a.z * b.z; acc[2][3] += a.z * b.w;
            acc[3][0] += a.w * b.x; acc[3][1] += a.w * b.y; acc[3][2] += a.w * b.z; acc[3][3] += a.w * b.w;
        }
        __syncthreads();
    }

    const float* xb = x + (size_t)n * CDIM * SDIM;
    #pragma unroll
    for (int i = 0; i < 4; i++) {
        const int m = m0 + ty * 4 + i;
        const float bv = bo[m];
        const float4 xv = *(const float4*)&xb[(size_t)m * SDIM + s0 + tx * 4];
        float4 v = make_float4(acc[i][0] + bv + xv.x, acc[i][1] + bv + xv.y,
                               acc[i][2] + bv + xv.z, acc[i][3] + bv + xv.w);
        *(float4*)&out[((size_t)n * CDIM + m) * SDIM + s0 + tx * 4] = v;
    }
}

// ---------------------------------------------------------------------------
extern "C" void kernel_launch(void* const* d_in, const int* in_sizes, int n_in,
                              void* d_out, int out_size, void* d_ws, size_t ws_size,
                              hipStream_t stream)
{
    const float* x  = (const float*)d_in[0];
    const float* Wg = (const float*)d_in[1];
    const float* bg = (const float*)d_in[2];
    const float* Wt = (const float*)d_in[3];
    const float* bt = (const float*)d_in[4];
    const float* Wp = (const float*)d_in[5];
    const float* bp = (const float*)d_in[6];
    const float* Wo = (const float*)d_in[7];
    const float* bo = (const float*)d_in[8];

    const size_t half_buf = (size_t)NBATCH * CDIM * SDIM * sizeof(f16);  // 8 MB
    char* wsb = (char*)d_ws;
    f16*   theta = (f16*)(wsb);
    f16*   phi   = (f16*)(wsb + half_buf);
    f16*   g     = (f16*)(wsb + 2 * half_buf);
    float* y     = (float*)(wsb + 3 * half_buf);
    float* out   = (float*)d_out;

    proj_kernel<<<dim3(SDIM / 64, CDIM / 64, NBATCH * 3), 256, 0, stream>>>(
        x, Wt, bt, Wp, bp, Wg, bg, theta, phi, g);
    attn_kernel<<<dim3(NBATCH * (SDIM / 64)), 256, 0, stream>>>(theta, phi, g, y);
    outproj_kernel<<<dim3(SDIM / 64, CDIM / 64, NBATCH), 256, 0, stream>>>(
        y, Wo, bo, x, out);
}

// Round 3
// 411.581 us; speedup vs baseline: 8.0156x; 1.4172x over previous
//
#include <hip/hip_runtime.h>
#include <math.h>

#define CDIM 256
#define SDIM 4096
#define NBATCH 4

typedef _Float16 f16;
typedef _Float16 f16x4 __attribute__((ext_vector_type(4)));
typedef _Float16 f16x8 __attribute__((ext_vector_type(8)));
typedef float    f32x16 __attribute__((ext_vector_type(16)));

// ---------------------------------------------------------------------------
// Kernel 1: fused 1x1-conv projections (fp32 compute, f16 outputs).
//   theta_t[n][s][c], phi_t[n][s][c]  (s,c)  -> MFMA A/B frags contiguous
//   g      [n][c][s]                  (c,s)  -> PV A-frag rows contiguous
// theta/phi stores go through an LDS transpose tile for 16B-coalesced writes.
// ---------------------------------------------------------------------------
__global__ __launch_bounds__(256)
void proj_kernel(const float* __restrict__ x,
                 const float* __restrict__ Wt, const float* __restrict__ bt,
                 const float* __restrict__ Wp, const float* __restrict__ bp,
                 const float* __restrict__ Wg, const float* __restrict__ bg,
                 f16* __restrict__ theta_t, f16* __restrict__ phi_t,
                 f16* __restrict__ g_out)
{
    const int p = blockIdx.z % 3;           // 0: theta, 1: phi, 2: g
    const int n = blockIdx.z / 3;
    const float* W    = (p == 0) ? Wt : (p == 1) ? Wp : Wg;
    const float* bias = (p == 0) ? bt : (p == 1) ? bp : bg;
    const float* xb = x + (size_t)n * CDIM * SDIM;

    const int s0 = blockIdx.x * 64;
    const int m0 = blockIdx.y * 64;

    __shared__ float As[16][68];   // W tile, [k][m]
    __shared__ float Bs[16][68];   // x tile, [k][s]
    __shared__ f16   Ts[64][72];   // transpose tile [s][c] for p<2 epilogue

    const int t  = threadIdx.x;
    const int tx = t & 15;         // s-frag /4
    const int ty = t >> 4;         // m-frag /4

    float acc[4][4] = {};

    for (int k0 = 0; k0 < CDIM; k0 += 16) {
        {
            const int ka = t & 15, ma = t >> 4;
            #pragma unroll
            for (int i = 0; i < 4; i++)
                As[ka][ma + 16 * i] = W[(size_t)(m0 + ma + 16 * i) * CDIM + k0 + ka];
            const int sb = t & 63, cb = t >> 6;
            #pragma unroll
            for (int i = 0; i < 4; i++)
                Bs[cb + 4 * i][sb] = xb[(size_t)(k0 + cb + 4 * i) * SDIM + s0 + sb];
        }
        __syncthreads();
        #pragma unroll
        for (int kk = 0; kk < 16; kk++) {
            const float4 a = *(const float4*)&As[kk][ty * 4];
            const float4 b = *(const float4*)&Bs[kk][tx * 4];
            acc[0][0] += a.x * b.x; acc[0][1] += a.x * b.y; acc[0][2] += a.x * b.z; acc[0][3] += a.x * b.w;
            acc[1][0] += a.y * b.x; acc[1][1] += a.y * b.y; acc[1][2] += a.y * b.z; acc[1][3] += a.y * b.w;
            acc[2][0] += a.z * b.x; acc[2][1] += a.z * b.y; acc[2][2] += a.z * b.z; acc[2][3] += a.z * b.w;
            acc[3][0] += a.w * b.x; acc[3][1] += a.w * b.y; acc[3][2] += a.w * b.z; acc[3][3] += a.w * b.w;
        }
        __syncthreads();
    }

    if (p < 2) {
        // write transposed (s, c) f16 via LDS transpose, coalesced 16B stores
        float bv[4];
        #pragma unroll
        for (int i = 0; i < 4; i++) bv[i] = bias[m0 + ty * 4 + i];
        #pragma unroll
        for (int j = 0; j < 4; j++)
            #pragma unroll
            for (int i = 0; i < 4; i++)
                Ts[tx * 4 + j][ty * 4 + i] = (f16)(acc[i][j] + bv[i]);
        __syncthreads();
        f16* out = ((p == 0) ? theta_t : phi_t) + (size_t)n * SDIM * CDIM;
        const int r2 = t >> 2, c2 = (t & 3) * 16;
        f16x8 v0 = *(f16x8*)&Ts[r2][c2];
        f16x8 v1 = *(f16x8*)&Ts[r2][c2 + 8];
        *(f16x8*)&out[(size_t)(s0 + r2) * CDIM + m0 + c2]     = v0;
        *(f16x8*)&out[(size_t)(s0 + r2) * CDIM + m0 + c2 + 8] = v1;
    } else {
        // (c, s) f16 output
        f16* out = g_out + (size_t)n * CDIM * SDIM;
        #pragma unroll
        for (int i = 0; i < 4; i++) {
            const int m = m0 + ty * 4 + i;
            const float bv = bias[m];
            f16x4 v;
            v[0] = (f16)(acc[i][0] + bv);
            v[1] = (f16)(acc[i][1] + bv);
            v[2] = (f16)(acc[i][2] + bv);
            v[3] = (f16)(acc[i][3] + bv);
            *(f16x4*)&out[(size_t)m * SDIM + s0 + tx * 4] = v;
        }
    }
}

// ---------------------------------------------------------------------------
// Kernel 2: MFMA flash attention, 2-way key split, register-prefetch pipeline.
// Block = 64 queries x 2048 keys (split = blockIdx.y). 512 blocks = 2/CU.
// Writes UNNORMALIZED partial O (c,s layout) + per-query (m, l) to workspace;
// the combine happens inside outproj_kernel's staging.
// Per 64-key chunk: [store phiP->LDS | A | issue gP loads, S-MFMA, Ps_raw | B |
//  store gP->LDS, softmax, Ps_h | C | issue next phiP loads, rescale, PV | D]
// MFMA frag model (32x32x16_f16): A[m][k]: m=lane%32, k=8*(lane/32)+i ;
// B[k][n]: n=lane%32 ; C/D: col=lane&31, row=(reg&3)+8*(reg>>2)+4*(lane>>5).
// ---------------------------------------------------------------------------
__global__ __launch_bounds__(256, 2)
void attn_kernel(const f16* __restrict__ theta,
                 const f16* __restrict__ phi,
                 const f16* __restrict__ g,
                 float* __restrict__ Op,     // [2][n][c][s] partial O
                 float* __restrict__ pm,     // [2][n][s]
                 float* __restrict__ pl)     // [2][n][s]
{
    const int bid   = blockIdx.x;
    const int n     = bid >> 6;
    const int q0    = (bid & 63) * 64;
    const int split = blockIdx.y;
    const int koff  = split * (SDIM / 2);
    const int kend  = koff + (SDIM / 2);

    __shared__ f16x8 bufA[2048];        // 32 KB: phi chunk, then G chunk
    __shared__ float Ps_raw[64][68];    // raw logits fp32
    __shared__ f16x8 Ps_h[512];         // P in B-frag layout [kgrp8][q64]
    __shared__ float m_s[64], l_s[64], alpha_s[64];

    const int t  = threadIdx.x;
    const int w  = t >> 6;
    const int l  = t & 63;
    const int wm = w & 1;               // query 32-half
    const int wn = w >> 1;              // key tile (S) / channel 128-half (PV)
    const int ln = l & 31;
    const int hi = l >> 5;

    const f16* thb = theta + (size_t)n * SDIM * CDIM;
    const f16* phb = phi   + (size_t)n * SDIM * CDIM;
    const f16* gb  = g     + (size_t)n * CDIM * SDIM;

    // theta A-fragments for this wave's 32 queries (resident all kernel)
    f16x8 aF[16];
    {
        const f16* ap = thb + (size_t)(q0 + 32 * wm + ln) * CDIM + hi * 8;
        #pragma unroll
        for (int j = 0; j < 16; ++j)
            aF[j] = *(const f16x8*)(ap + 16 * j);
    }

    f32x16 O[4];
    #pragma unroll
    for (int mt = 0; mt < 4; ++mt)
        #pragma unroll
        for (int r = 0; r < 16; ++r) O[mt][r] = 0.0f;

    if (t < 64) { m_s[t] = -INFINITY; l_s[t] = 0.0f; }

    // staging index helpers (fixed per thread)
    const int pkey = (t >> 5) * 8;      // base handled via it loop below
    (void)pkey;

    // initial phi prefetch (chunk 0 of this split)
    f16x8 phiP[8];
    #pragma unroll
    for (int it = 0; it < 8; ++it) {
        const int id  = it * 256 + t;
        const int key = id >> 5;
        const int grp = id & 31;
        phiP[it] = *(const f16x8*)(phb + (size_t)(koff + key) * CDIM + grp * 8);
    }

    for (int k0 = koff; k0 < kend; k0 += 64) {
        // ---- store prefetched phi chunk into LDS (swizzled) ----
        #pragma unroll
        for (int it = 0; it < 8; ++it) {
            const int id  = it * 256 + t;
            const int key = id >> 5;
            const int grp = id & 31;
            bufA[key * 32 + (grp ^ (key & 31))] = phiP[it];
        }
        __syncthreads();                                   // A

        // ---- issue G loads for this chunk (latency hides behind S) ----
        f16x8 gP[8];
        #pragma unroll
        for (int it = 0; it < 8; ++it) {
            const int chan = it * 32 + (t >> 3);
            const int kg   = t & 7;
            gP[it] = *(const f16x8*)(gb + (size_t)chan * SDIM + k0 + kg * 8);
        }

        // ---- S = theta^T phi (this wave: 32 q x 32 k, K=256) ----
        {
            f32x16 sC;
            #pragma unroll
            for (int r = 0; r < 16; ++r) sC[r] = 0.0f;
            const int key = 32 * wn + ln;
            #pragma unroll
            for (int j = 0; j < 16; ++j) {
                const int grp = 2 * j + hi;
                f16x8 b = bufA[key * 32 + (grp ^ (key & 31))];
                sC = __builtin_amdgcn_mfma_f32_32x32x16_f16(aF[j], b, sC, 0, 0, 0);
            }
            #pragma unroll
            for (int r = 0; r < 16; ++r) {
                const int row = (r & 3) + 8 * (r >> 2) + 4 * hi;
                Ps_raw[32 * wm + row][32 * wn + ln] = sC[r];
            }
        }
        __syncthreads();                                   // B

        // ---- store G chunk into LDS + cooperative online softmax ----
        #pragma unroll
        for (int it = 0; it < 8; ++it) {
            const int chan = it * 32 + (t >> 3);
            const int kg   = t & 7;
            bufA[kg * 256 + (chan ^ (kg << 2))] = gP[it];
        }
        {
            const int q  = t >> 2;
            const int qt = t & 3;
            float arr[16];
            *(float4*)&arr[0]  = *(const float4*)&Ps_raw[q][qt * 16 + 0];
            *(float4*)&arr[4]  = *(const float4*)&Ps_raw[q][qt * 16 + 4];
            *(float4*)&arr[8]  = *(const float4*)&Ps_raw[q][qt * 16 + 8];
            *(float4*)&arr[12] = *(const float4*)&Ps_raw[q][qt * 16 + 12];
            float mx = arr[0];
            #pragma unroll
            for (int i = 1; i < 16; ++i) mx = fmaxf(mx, arr[i]);
            mx = fmaxf(mx, __shfl_xor(mx, 1));
            mx = fmaxf(mx, __shfl_xor(mx, 2));
            const float mo = m_s[q];
            const float mn = fmaxf(mo, mx);
            const float al = __expf(mo - mn);
            float sum = 0.0f;
            #pragma unroll
            for (int i = 0; i < 16; ++i) {
                arr[i] = __expf(arr[i] - mn);
                sum += arr[i];
            }
            sum += __shfl_xor(sum, 1);
            sum += __shfl_xor(sum, 2);
            if (qt == 0) {
                m_s[q] = mn;
                alpha_s[q] = al;
                l_s[q] = l_s[q] * al + sum;
            }
            f16x8 h0, h1;
            #pragma unroll
            for (int i = 0; i < 8; ++i) { h0[i] = (f16)arr[i]; h1[i] = (f16)arr[8 + i]; }
            Ps_h[(2 * qt + 0) * 64 + q] = h0;
            Ps_h[(2 * qt + 1) * 64 + q] = h1;
        }
        __syncthreads();                                   // C

        // ---- prefetch next phi chunk (latency hides behind PV) ----
        if (k0 + 64 < kend) {
            #pragma unroll
            for (int it = 0; it < 8; ++it) {
                const int id  = it * 256 + t;
                const int key = id >> 5;
                const int grp = id & 31;
                phiP[it] = *(const f16x8*)(phb + (size_t)(k0 + 64 + key) * CDIM + grp * 8);
            }
        }

        // ---- PV: O^T += G^T P^T (this wave: 128 chans x 32 q, K=64 keys) ----
        {
            const float al = alpha_s[32 * wm + ln];
            if (__any(al != 1.0f)) {
                #pragma unroll
                for (int mt = 0; mt < 4; ++mt)
                    #pragma unroll
                    for (int r = 0; r < 16; ++r) O[mt][r] *= al;
            }
            #pragma unroll
            for (int st = 0; st < 4; ++st) {
                const int kc = 2 * st + hi;
                f16x8 pB = Ps_h[kc * 64 + 32 * wm + ln];
                #pragma unroll
                for (int mt = 0; mt < 4; ++mt) {
                    const int chan = 128 * wn + 32 * mt + ln;
                    f16x8 gA = bufA[kc * 256 + (chan ^ (kc << 2))];
                    O[mt] = __builtin_amdgcn_mfma_f32_32x32x16_f16(gA, pB, O[mt], 0, 0, 0);
                }
            }
        }
        __syncthreads();                                   // D
    }

    // ---- epilogue: write unnormalized partial O (c,s) + (m, l) ----
    {
        float* Opb = Op + ((size_t)(split * NBATCH + n)) * CDIM * SDIM;
        #pragma unroll
        for (int mt = 0; mt < 4; ++mt) {
            #pragma unroll
            for (int r = 0; r < 16; ++r) {
                const int row  = (r & 3) + 8 * (r >> 2) + 4 * hi;
                const int chan = 128 * wn + 32 * mt + row;
                Opb[(size_t)chan * SDIM + q0 + 32 * wm + ln] = O[mt][r];
            }
        }
        if (t < 64) {
            pm[(size_t)(split * NBATCH + n) * SDIM + q0 + t] = m_s[t];
            pl[(size_t)(split * NBATCH + n) * SDIM + q0 + t] = l_s[t];
        }
    }
}

// ---------------------------------------------------------------------------
// Kernel 3: output projection + residual, with the split-combine fused into
// the B staging. For each spatial s: M=max(m0,m1), sc_i = e^{mi-M}/denom,
// denom = e^{m0-M} l0 + e^{m1-M} l1; y[ci][s] = sc0*Op0[ci][s]+sc1*Op1[ci][s].
//   out[n][c][s] = x[n][c][s] + bo[c] + sum_ci Wo[c][ci] * y[ci][s]
// ---------------------------------------------------------------------------
__global__ __launch_bounds__(256)
void outproj_kernel(const float* __restrict__ Op,   // [2][n][c][s]
                    const float* __restrict__ pm,   // [2][n][s]
                    const float* __restrict__ pl,   // [2][n][s]
                    const float* __restrict__ Wo,
                    const float* __restrict__ bo,
                    const float* __restrict__ x,
                    float* __restrict__ out)
{
    const int n  = blockIdx.z;
    const int s0 = blockIdx.x * 64;
    const int m0 = blockIdx.y * 64;

    const size_t obuf = (size_t)NBATCH * CDIM * SDIM;
    const float* Op0 = Op + (size_t)n * CDIM * SDIM;
    const float* Op1 = Op0 + obuf;

    __shared__ float As[16][68];   // Wo tile [k][m]
    __shared__ float Bs[16][68];   // combined y tile [k][s]

    const int t = threadIdx.x, tx = t & 15, ty = t >> 4;

    // per-thread combine scales (s fixed per thread for the staging role)
    const int sb = t & 63, cb = t >> 6;
    float sc0, sc1;
    {
        const int s = s0 + sb;
        const float m0v = pm[(size_t)n * SDIM + s];
        const float m1v = pm[(size_t)(NBATCH + n) * SDIM + s];
        const float l0v = pl[(size_t)n * SDIM + s];
        const float l1v = pl[(size_t)(NBATCH + n) * SDIM + s];
        const float M   = fmaxf(m0v, m1v);
        const float e0  = __expf(m0v - M);
        const float e1  = __expf(m1v - M);
        const float rd  = 1.0f / (e0 * l0v + e1 * l1v);
        sc0 = e0 * rd;
        sc1 = e1 * rd;
    }

    float acc[4][4] = {};

    for (int k0 = 0; k0 < CDIM; k0 += 16) {
        {
            const int ka = t & 15, ma = t >> 4;
            #pragma unroll
            for (int i = 0; i < 4; i++)
                As[ka][ma + 16 * i] = Wo[(size_t)(m0 + ma + 16 * i) * CDIM + k0 + ka];
            #pragma unroll
            for (int i = 0; i < 4; i++) {
                const size_t idx = (size_t)(k0 + cb + 4 * i) * SDIM + s0 + sb;
                Bs[cb + 4 * i][sb] = sc0 * Op0[idx] + sc1 * Op1[idx];
            }
        }
        __syncthreads();
        #pragma unroll
        for (int kk = 0; kk < 16; kk++) {
            const float4 a = *(const float4*)&As[kk][ty * 4];
            const float4 b = *(const float4*)&Bs[kk][tx * 4];
            acc[0][0] += a.x * b.x; acc[0][1] += a.x * b.y; acc[0][2] += a.x * b.z; acc[0][3] += a.x * b.w;
            acc[1][0] += a.y * b.x; acc[1][1] += a.y * b.y; acc[1][2] += a.y * b.z; acc[1][3] += a.y * b.w;
            acc[2][0] += a.z * b.x; acc[2][1] += a.z * b.y; acc[2][2] += a.z * b.z; acc[2][3] += a.z * b.w;
            acc[3][0] += a.w * b.x; acc[3][1] += a.w * b.y; acc[3][2] += a.w * b.z; acc[3][3] += a.w * b.w;
        }
        __syncthreads();
    }

    const float* xb = x + (size_t)n * CDIM * SDIM;
    #pragma unroll
    for (int i = 0; i < 4; i++) {
        const int m = m0 + ty * 4 + i;
        const float bv = bo[m];
        const float4 xv = *(const float4*)&xb[(size_t)m * SDIM + s0 + tx * 4];
        float4 v = make_float4(acc[i][0] + bv + xv.x, acc[i][1] + bv + xv.y,
                               acc[i][2] + bv + xv.z, acc[i][3] + bv + xv.w);
        *(float4*)&out[((size_t)n * CDIM + m) * SDIM + s0 + tx * 4] = v;
    }
}

// ---------------------------------------------------------------------------
extern "C" void kernel_launch(void* const* d_in, const int* in_sizes, int n_in,
                              void* d_out, int out_size, void* d_ws, size_t ws_size,
                              hipStream_t stream)
{
    const float* x  = (const float*)d_in[0];
    const float* Wg = (const float*)d_in[1];
    const float* bg = (const float*)d_in[2];
    const float* Wt = (const float*)d_in[3];
    const float* bt = (const float*)d_in[4];
    const float* Wp = (const float*)d_in[5];
    const float* bp = (const float*)d_in[6];
    const float* Wo = (const float*)d_in[7];
    const float* bo = (const float*)d_in[8];

    const size_t half_buf = (size_t)NBATCH * CDIM * SDIM * sizeof(f16);   // 8 MB
    const size_t obuf     = (size_t)NBATCH * CDIM * SDIM * sizeof(float); // 16 MB
    const size_t mlbuf    = (size_t)NBATCH * SDIM * sizeof(float);        // 64 KB
    char* wsb = (char*)d_ws;
    f16*   theta = (f16*)(wsb);
    f16*   phi   = (f16*)(wsb + half_buf);
    f16*   g     = (f16*)(wsb + 2 * half_buf);
    float* Op    = (float*)(wsb + 3 * half_buf);             // [2] partials
    float* pm    = (float*)(wsb + 3 * half_buf + 2 * obuf);  // [2][n][s]
    float* pl    = (float*)(wsb + 3 * half_buf + 2 * obuf + 2 * mlbuf);
    float* out   = (float*)d_out;

    proj_kernel<<<dim3(SDIM / 64, CDIM / 64, NBATCH * 3), 256, 0, stream>>>(
        x, Wt, bt, Wp, bp, Wg, bg, theta, phi, g);
    attn_kernel<<<dim3(NBATCH * (SDIM / 64), 2), 256, 0, stream>>>(
        theta, phi, g, Op, pm, pl);
    outproj_kernel<<<dim3(SDIM / 64, CDIM / 64, NBATCH), 256, 0, stream>>>(
        Op, pm, pl, Wo, bo, x, out);
}

// Round 4
// 335.451 us; speedup vs baseline: 9.8347x; 1.2269x over previous
//
#include <hip/hip_runtime.h>
#include <math.h>

#define CDIM 256
#define SDIM 4096
#define NBATCH 4

typedef _Float16 f16;
typedef _Float16 f16x4 __attribute__((ext_vector_type(4)));
typedef _Float16 f16x8 __attribute__((ext_vector_type(8)));
typedef float    f32x16 __attribute__((ext_vector_type(16)));

// async 16B global->LDS (DMA, no VGPR round-trip). LDS dest must be
// wave-uniform; HW writes lds + lane*16. Source ptr is per-lane.
__device__ __forceinline__ void gload_lds16(const f16* gp, void* lp) {
    __builtin_amdgcn_global_load_lds(
        (const __attribute__((address_space(1))) void*)gp,
        (__attribute__((address_space(3))) void*)lp, 16, 0, 0);
}

// ---------------------------------------------------------------------------
// Kernel 1: fused 1x1-conv projections (fp32 compute, f16 outputs).
//   theta_t[n][s][c], phi_t[n][s][c]  (s,c) ; g [n][c][s]  (c,s)
// ---------------------------------------------------------------------------
__global__ __launch_bounds__(256)
void proj_kernel(const float* __restrict__ x,
                 const float* __restrict__ Wt, const float* __restrict__ bt,
                 const float* __restrict__ Wp, const float* __restrict__ bp,
                 const float* __restrict__ Wg, const float* __restrict__ bg,
                 f16* __restrict__ theta_t, f16* __restrict__ phi_t,
                 f16* __restrict__ g_out)
{
    const int p = blockIdx.z % 3;           // 0: theta, 1: phi, 2: g
    const int n = blockIdx.z / 3;
    const float* W    = (p == 0) ? Wt : (p == 1) ? Wp : Wg;
    const float* bias = (p == 0) ? bt : (p == 1) ? bp : bg;
    const float* xb = x + (size_t)n * CDIM * SDIM;

    const int s0 = blockIdx.x * 64;
    const int m0 = blockIdx.y * 64;

    __shared__ float As[16][68];
    __shared__ float Bs[16][68];
    __shared__ f16   Ts[64][72];

    const int t  = threadIdx.x;
    const int tx = t & 15;
    const int ty = t >> 4;

    float acc[4][4] = {};

    for (int k0 = 0; k0 < CDIM; k0 += 16) {
        {
            const int ka = t & 15, ma = t >> 4;
            #pragma unroll
            for (int i = 0; i < 4; i++)
                As[ka][ma + 16 * i] = W[(size_t)(m0 + ma + 16 * i) * CDIM + k0 + ka];
            const int sb = t & 63, cb = t >> 6;
            #pragma unroll
            for (int i = 0; i < 4; i++)
                Bs[cb + 4 * i][sb] = xb[(size_t)(k0 + cb + 4 * i) * SDIM + s0 + sb];
        }
        __syncthreads();
        #pragma unroll
        for (int kk = 0; kk < 16; kk++) {
            const float4 a = *(const float4*)&As[kk][ty * 4];
            const float4 b = *(const float4*)&Bs[kk][tx * 4];
            acc[0][0] += a.x * b.x; acc[0][1] += a.x * b.y; acc[0][2] += a.x * b.z; acc[0][3] += a.x * b.w;
            acc[1][0] += a.y * b.x; acc[1][1] += a.y * b.y; acc[1][2] += a.y * b.z; acc[1][3] += a.y * b.w;
            acc[2][0] += a.z * b.x; acc[2][1] += a.z * b.y; acc[2][2] += a.z * b.z; acc[2][3] += a.z * b.w;
            acc[3][0] += a.w * b.x; acc[3][1] += a.w * b.y; acc[3][2] += a.w * b.z; acc[3][3] += a.w * b.w;
        }
        __syncthreads();
    }

    if (p < 2) {
        float bv[4];
        #pragma unroll
        for (int i = 0; i < 4; i++) bv[i] = bias[m0 + ty * 4 + i];
        #pragma unroll
        for (int j = 0; j < 4; j++)
            #pragma unroll
            for (int i = 0; i < 4; i++)
                Ts[tx * 4 + j][ty * 4 + i] = (f16)(acc[i][j] + bv[i]);
        __syncthreads();
        f16* out = ((p == 0) ? theta_t : phi_t) + (size_t)n * SDIM * CDIM;
        const int r2 = t >> 2, c2 = (t & 3) * 16;
        f16x8 v0 = *(f16x8*)&Ts[r2][c2];
        f16x8 v1 = *(f16x8*)&Ts[r2][c2 + 8];
        *(f16x8*)&out[(size_t)(s0 + r2) * CDIM + m0 + c2]     = v0;
        *(f16x8*)&out[(size_t)(s0 + r2) * CDIM + m0 + c2 + 8] = v1;
    } else {
        f16* out = g_out + (size_t)n * CDIM * SDIM;
        #pragma unroll
        for (int i = 0; i < 4; i++) {
            const int m = m0 + ty * 4 + i;
            const float bv = bias[m];
            f16x4 v;
            v[0] = (f16)(acc[i][0] + bv);
            v[1] = (f16)(acc[i][1] + bv);
            v[2] = (f16)(acc[i][2] + bv);
            v[3] = (f16)(acc[i][3] + bv);
            *(f16x4*)&out[(size_t)m * SDIM + s0 + tx * 4] = v;
        }
    }
}

// ---------------------------------------------------------------------------
// Kernel 2: MFMA flash attention, S^T orientation, in-register softmax,
// global_load_lds staging, double-buffered, 1 barrier/chunk.
//
// Block: 256 thr = 4 waves; wave w owns queries [q0+32w, q0+32w+32), all 256
// output channels. 128 q/block. blockIdx.y = key split (2 x 2048 keys).
// Chunk = 32 keys. Grid 4*32 x 2 = 256 blocks = 1/CU.
//
// Layout model (validated rounds 2-3, mfma_f32_32x32x16_f16):
//   A[m][k]: m=lane&31, k=8*(lane>>5)+i   (f16x8 per lane)
//   B[k][n]: n=lane&31, k=8*(lane>>5)+i
//   C/D:     col=lane&31, row=(r&3)+8*(r>>2)+4*(lane>>5)
//
// S^T = phi(A) x theta^T(B): col = q -> each lane pair (ln, ln+32) holds all
// 32 keys of query q0+32w+ln. Softmax = reg-tree + shfl_xor(32). P repack to
// PV B-frags: frag[ks][i] needs key 16ks+8hi+i = exp'd reg (i&3)+8ks+4hi of
// lane (ln, i>>2); own half direct, other half via shfl_xor(32).
// PV: O^T = G(A) x P^T(B), 8 chan-tiles x 2 ksteps per chunk.
// ---------------------------------------------------------------------------
__global__ __launch_bounds__(256, 1)
void attn_kernel(const f16* __restrict__ theta,
                 const f16* __restrict__ phi,
                 const f16* __restrict__ g,
                 f16* __restrict__ Op,       // [2][n][c][s] unnormalized, f16
                 float* __restrict__ pm,     // [2][n][s]
                 float* __restrict__ pl)     // [2][n][s]
{
    const int bx    = blockIdx.x;
    const int n     = bx >> 5;
    const int q0    = (bx & 31) * 128;
    const int split = blockIdx.y;
    const int koff  = split * (SDIM / 2);
    const int NCH   = (SDIM / 2) / 32;      // 64 chunks

    // 64 KB total LDS, double-buffered 16 KB phi + 16 KB G
    __shared__ f16x8 bufP[2][1024];         // [key 0..31][grp^key]
    __shared__ f16x8 bufG[2][1024];         // [kg 0..3][chan^(kg<<2)]

    const int t  = threadIdx.x;
    const int w  = t >> 6;
    const int l  = t & 63;
    const int ln = l & 31;
    const int hi = l >> 5;

    const f16* thb = theta + (size_t)n * SDIM * CDIM;
    const f16* phb = phi   + (size_t)n * SDIM * CDIM;
    const f16* gb  = g     + (size_t)n * CDIM * SDIM;

    const int myq = q0 + 32 * w + ln;

    // theta B-fragments (resident, 64 VGPRs): bT[j] = theta[myq][16j+8hi .. +8]
    f16x8 bT[16];
    {
        const f16* ap = thb + (size_t)myq * CDIM + hi * 8;
        #pragma unroll
        for (int j = 0; j < 16; ++j)
            bT[j] = *(const f16x8*)(ap + 16 * j);
    }

    f32x16 O[8];
    #pragma unroll
    for (int ct = 0; ct < 8; ++ct)
        #pragma unroll
        for (int r = 0; r < 16; ++r) O[ct][r] = 0.0f;

    float m_run = -INFINITY, l_run = 0.0f;

    // ---- staging: issue chunk at key-base k0 into buffer b ----
    // phi slots: slot = key*32 + (grp ^ key); lds writes lane-ordered, so
    // invert: key = slot>>5, grp = (slot&31)^key, source = phi[k0+key][grp*8].
    // G slots: slot = kg*256 + (chan ^ (kg<<2)); kg = slot>>8,
    // chan = (slot&255)^(kg<<2), source = g[chan][k0+kg*8].
#define ISSUE_CHUNK(k0, b)                                                    \
    {                                                                         \
        _Pragma("unroll")                                                     \
        for (int it = 0; it < 4; ++it) {                                      \
            const int slot = w * 256 + it * 64 + l;                           \
            const int key  = slot >> 5;                                       \
            const int grp  = (slot & 31) ^ key;                               \
            gload_lds16(phb + (size_t)((k0) + key) * CDIM + grp * 8,          \
                        &bufP[b][w * 256 + it * 64]);                         \
        }                                                                     \
        _Pragma("unroll")                                                     \
        for (int it = 0; it < 4; ++it) {                                      \
            const int slot = w * 256 + it * 64 + l;                           \
            const int kg   = slot >> 8;                                       \
            const int chan = (slot & 255) ^ (kg << 2);                        \
            gload_lds16(gb + (size_t)chan * SDIM + (k0) + kg * 8,             \
                        &bufG[b][w * 256 + it * 64]);                         \
        }                                                                     \
    }

    ISSUE_CHUNK(koff, 0);

    for (int ci = 0; ci < NCH; ++ci) {
        const int b = ci & 1;
        __syncthreads();   // drains DMA for chunk ci; frees buf b^1
        if (ci + 1 < NCH) ISSUE_CHUNK(koff + (ci + 1) * 32, b ^ 1);

        // ---- S^T = phi x theta^T : 32 keys x 32 q, K=256 ----
        f32x16 sC;
        #pragma unroll
        for (int r = 0; r < 16; ++r) sC[r] = 0.0f;
        #pragma unroll
        for (int j = 0; j < 16; ++j) {
            const int grp = 2 * j + hi;
            f16x8 a = bufP[b][ln * 32 + (grp ^ ln)];
            sC = __builtin_amdgcn_mfma_f32_32x32x16_f16(a, bT[j], sC, 0, 0, 0);
        }
        // lane (ln,hi) reg r: key=(r&3)+8*(r>>2)+4hi, q=myq (same all regs)

        // ---- in-register online softmax for query myq ----
        float mx = sC[0];
        #pragma unroll
        for (int r = 1; r < 16; ++r) mx = fmaxf(mx, sC[r]);
        mx = fmaxf(mx, __shfl_xor(mx, 32));
        const float mn = fmaxf(m_run, mx);
        const float al = __expf(m_run - mn);
        m_run = mn;
        float sum = 0.0f;
        #pragma unroll
        for (int r = 0; r < 16; ++r) {
            sC[r] = __expf(sC[r] - mn);
            sum += sC[r];
        }
        sum += __shfl_xor(sum, 32);
        l_run = l_run * al + sum;

        if (__any(al != 1.0f)) {
            #pragma unroll
            for (int ct = 0; ct < 8; ++ct)
                #pragma unroll
                for (int r = 0; r < 16; ++r) O[ct][r] *= al;
        }

        // ---- repack P to PV B-frags: pf[ks][i] = P[key=16ks+8hi+i][myq] ----
        f16x8 pf[2];
        #pragma unroll
        for (int ks = 0; ks < 2; ++ks) {
            #pragma unroll
            for (int j = 0; j < 4; ++j) {
                const float own = hi ? sC[8 * ks + 4 + j] : sC[8 * ks + j];
                const float oth = hi ? sC[8 * ks + j]     : sC[8 * ks + 4 + j];
                const float par = __shfl_xor(oth, 32);
                pf[ks][j]     = (f16)(hi ? par : own);
                pf[ks][4 + j] = (f16)(hi ? own : par);
            }
        }

        // ---- PV: O^T += G x P^T (256 chan x 32 q, K=32 keys) ----
        #pragma unroll
        for (int ks = 0; ks < 2; ++ks) {
            const int kg = 2 * ks + hi;
            #pragma unroll
            for (int ct = 0; ct < 8; ++ct) {
                f16x8 ga = bufG[b][kg * 256 + ((32 * ct + ln) ^ (kg << 2))];
                O[ct] = __builtin_amdgcn_mfma_f32_32x32x16_f16(ga, pf[ks], O[ct], 0, 0, 0);
            }
        }
    }

    // ---- epilogue: unnormalized partial O (f16, c-s layout) + (m, l) ----
    {
        f16* Opb = Op + ((size_t)(split * NBATCH + n)) * CDIM * SDIM;
        #pragma unroll
        for (int ct = 0; ct < 8; ++ct) {
            #pragma unroll
            for (int r = 0; r < 16; ++r) {
                const int chan = 32 * ct + (r & 3) + 8 * (r >> 2) + 4 * hi;
                Opb[(size_t)chan * SDIM + myq] = (f16)O[ct][r];
            }
        }
        if (hi == 0) {
            pm[(size_t)(split * NBATCH + n) * SDIM + myq] = m_run;
            pl[(size_t)(split * NBATCH + n) * SDIM + myq] = l_run;
        }
    }
#undef ISSUE_CHUNK
}

// ---------------------------------------------------------------------------
// Kernel 3: output projection + residual, split-combine fused into staging.
//   y[ci][s] = sc0*Op0[ci][s] + sc1*Op1[ci][s]   (Op now f16)
//   out[n][c][s] = x + bo + Wo @ y
// ---------------------------------------------------------------------------
__global__ __launch_bounds__(256)
void outproj_kernel(const f16* __restrict__ Op,    // [2][n][c][s] f16
                    const float* __restrict__ pm,
                    const float* __restrict__ pl,
                    const float* __restrict__ Wo,
                    const float* __restrict__ bo,
                    const float* __restrict__ x,
                    float* __restrict__ out)
{
    const int n  = blockIdx.z;
    const int s0 = blockIdx.x * 64;
    const int m0 = blockIdx.y * 64;

    const size_t obuf = (size_t)NBATCH * CDIM * SDIM;
    const f16* Op0 = Op + (size_t)n * CDIM * SDIM;
    const f16* Op1 = Op0 + obuf;

    __shared__ float As[16][68];
    __shared__ float Bs[16][68];

    const int t = threadIdx.x, tx = t & 15, ty = t >> 4;

    const int sb = t & 63, cb = t >> 6;
    float sc0, sc1;
    {
        const int s = s0 + sb;
        const float m0v = pm[(size_t)n * SDIM + s];
        const float m1v = pm[(size_t)(NBATCH + n) * SDIM + s];
        const float l0v = pl[(size_t)n * SDIM + s];
        const float l1v = pl[(size_t)(NBATCH + n) * SDIM + s];
        const float M   = fmaxf(m0v, m1v);
        const float e0  = __expf(m0v - M);
        const float e1  = __expf(m1v - M);
        const float rd  = 1.0f / (e0 * l0v + e1 * l1v);
        sc0 = e0 * rd;
        sc1 = e1 * rd;
    }

    float acc[4][4] = {};

    for (int k0 = 0; k0 < CDIM; k0 += 16) {
        {
            const int ka = t & 15, ma = t >> 4;
            #pragma unroll
            for (int i = 0; i < 4; i++)
                As[ka][ma + 16 * i] = Wo[(size_t)(m0 + ma + 16 * i) * CDIM + k0 + ka];
            #pragma unroll
            for (int i = 0; i < 4; i++) {
                const size_t idx = (size_t)(k0 + cb + 4 * i) * SDIM + s0 + sb;
                Bs[cb + 4 * i][sb] = sc0 * (float)Op0[idx] + sc1 * (float)Op1[idx];
            }
        }
        __syncthreads();
        #pragma unroll
        for (int kk = 0; kk < 16; kk++) {
            const float4 a = *(const float4*)&As[kk][ty * 4];
            const float4 b = *(const float4*)&Bs[kk][tx * 4];
            acc[0][0] += a.x * b.x; acc[0][1] += a.x * b.y; acc[0][2] += a.x * b.z; acc[0][3] += a.x * b.w;
            acc[1][0] += a.y * b.x; acc[1][1] += a.y * b.y; acc[1][2] += a.y * b.z; acc[1][3] += a.y * b.w;
            acc[2][0] += a.z * b.x; acc[2][1] += a.z * b.y; acc[2][2] += a.z * b.z; acc[2][3] += a.z * b.w;
            acc[3][0] += a.w * b.x; acc[3][1] += a.w * b.y; acc[3][2] += a.w * b.z; acc[3][3] += a.w * b.w;
        }
        __syncthreads();
    }

    const float* xb = x + (size_t)n * CDIM * SDIM;
    #pragma unroll
    for (int i = 0; i < 4; i++) {
        const int m = m0 + ty * 4 + i;
        const float bv = bo[m];
        const float4 xv = *(const float4*)&xb[(size_t)m * SDIM + s0 + tx * 4];
        float4 v = make_float4(acc[i][0] + bv + xv.x, acc[i][1] + bv + xv.y,
                               acc[i][2] + bv + xv.z, acc[i][3] + bv + xv.w);
        *(float4*)&out[((size_t)n * CDIM + m) * SDIM + s0 + tx * 4] = v;
    }
}

// ---------------------------------------------------------------------------
extern "C" void kernel_launch(void* const* d_in, const int* in_sizes, int n_in,
                              void* d_out, int out_size, void* d_ws, size_t ws_size,
                              hipStream_t stream)
{
    const float* x  = (const float*)d_in[0];
    const float* Wg = (const float*)d_in[1];
    const float* bg = (const float*)d_in[2];
    const float* Wt = (const float*)d_in[3];
    const float* bt = (const float*)d_in[4];
    const float* Wp = (const float*)d_in[5];
    const float* bp = (const float*)d_in[6];
    const float* Wo = (const float*)d_in[7];
    const float* bo = (const float*)d_in[8];

    const size_t half_buf = (size_t)NBATCH * CDIM * SDIM * sizeof(f16);   // 8 MB
    const size_t mlbuf    = (size_t)NBATCH * SDIM * sizeof(float);        // 64 KB
    char* wsb = (char*)d_ws;
    f16*   theta = (f16*)(wsb);
    f16*   phi   = (f16*)(wsb + half_buf);
    f16*   g     = (f16*)(wsb + 2 * half_buf);
    f16*   Op    = (f16*)(wsb + 3 * half_buf);               // [2] partials, 16 MB
    float* pm    = (float*)(wsb + 5 * half_buf);
    float* pl    = (float*)(wsb + 5 * half_buf + 2 * mlbuf);
    float* out   = (float*)d_out;

    proj_kernel<<<dim3(SDIM / 64, CDIM / 64, NBATCH * 3), 256, 0, stream>>>(
        x, Wt, bt, Wp, bp, Wg, bg, theta, phi, g);
    attn_kernel<<<dim3(NBATCH * (SDIM / 128), 2), 256, 0, stream>>>(
        theta, phi, g, Op, pm, pl);
    outproj_kernel<<<dim3(SDIM / 64, CDIM / 64, NBATCH), 256, 0, stream>>>(
        Op, pm, pl, Wo, bo, x, out);
}

// Round 5
// 318.351 us; speedup vs baseline: 10.3630x; 1.0537x over previous
//
#include <hip/hip_runtime.h>
#include <math.h>

#define CDIM 256
#define SDIM 4096
#define NBATCH 4

typedef _Float16 f16;
typedef _Float16 f16x4 __attribute__((ext_vector_type(4)));
typedef _Float16 f16x8 __attribute__((ext_vector_type(8)));
typedef float    f32x16 __attribute__((ext_vector_type(16)));

union PK2 { f16 h[2]; unsigned u; };
union CV8 { f16x8 v; uint2 q[2]; };

// async 16B global->LDS DMA; LDS dest wave-uniform base, HW scatters lane*16.
__device__ __forceinline__ void gload_lds16(const f16* gp, void* lp) {
    __builtin_amdgcn_global_load_lds(
        (const __attribute__((address_space(1))) void*)gp,
        (__attribute__((address_space(3))) void*)lp, 16, 0, 0);
}

// MFMA frag model (validated rounds 2-4, mfma_f32_32x32x16_f16):
//   A[m][k]: m=lane&31, frag j covers k=16j+8*(lane>>5)+(0..7)
//   B[k][n]: n=lane&31, same k pattern
//   C/D:     col=lane&31, row=(r&3)+8*(r>>2)+4*(lane>>5)

// ---------------------------------------------------------------------------
// Kernel 1: MFMA 1x1-conv projections. One proj per blockIdx.z (n*3+p).
// Tile 128 c_out x 128 s, K=256 in 4 chunks of 64, dbuf LDS, W frags resident.
//   theta_t/phi_t: (s,c) f16 via LDS transpose; g: (c,s) f16 direct.
// ---------------------------------------------------------------------------
__global__ __launch_bounds__(256, 2)
void proj_kernel(const float* __restrict__ x,
                 const float* __restrict__ Wt, const float* __restrict__ bt,
                 const float* __restrict__ Wp, const float* __restrict__ bp,
                 const float* __restrict__ Wg, const float* __restrict__ bg,
                 f16* __restrict__ theta_t, f16* __restrict__ phi_t,
                 f16* __restrict__ g_out)
{
    const int p = blockIdx.z % 3;
    const int n = blockIdx.z / 3;
    const float* W    = (p == 0) ? Wt : (p == 1) ? Wp : Wg;
    const float* bias = (p == 0) ? bt : (p == 1) ? bp : bg;
    const float* xb = x + (size_t)n * CDIM * SDIM;
    const int s0 = blockIdx.x * 128;
    const int m0 = blockIdx.y * 128;

    // union: staging xs[2][128][34] dwords (34816 B) / transpose tr[128][136] f16
    __shared__ __align__(16) char smraw[34816];
    unsigned (*xs)[128][34] = reinterpret_cast<unsigned (*)[128][34]>(smraw);
    f16 (*tr)[136]          = reinterpret_cast<f16 (*)[136]>(smraw);

    const int t = threadIdx.x, w = t >> 6, l = t & 63, ln = l & 31, hi = l >> 5;
    const int wm = w & 1, wn = w >> 1;

    // resident W A-frags (fp32 -> f16), 64 VGPR
    f16x8 aW[2][16];
    #pragma unroll
    for (int mt = 0; mt < 2; ++mt) {
        const float* wr = W + (size_t)(m0 + 64 * wm + 32 * mt + ln) * CDIM + 8 * hi;
        #pragma unroll
        for (int j = 0; j < 16; ++j) {
            float4 u0 = *(const float4*)(wr + 16 * j);
            float4 u1 = *(const float4*)(wr + 16 * j + 4);
            f16x8 v;
            v[0] = (f16)u0.x; v[1] = (f16)u0.y; v[2] = (f16)u0.z; v[3] = (f16)u0.w;
            v[4] = (f16)u1.x; v[5] = (f16)u1.y; v[6] = (f16)u1.z; v[7] = (f16)u1.w;
            aW[mt][j] = v;
        }
    }

    f32x16 acc[2][2];
    #pragma unroll
    for (int a = 0; a < 2; ++a)
        #pragma unroll
        for (int b = 0; b < 2; ++b)
            #pragma unroll
            for (int r = 0; r < 16; ++r) acc[a][b][r] = 0.0f;

    const int sL = t & 127;            // staging: thread owns column s0+sL
    const int kB = (t >> 7) * 32;      // and k rows kB..kB+31 of the 64-chunk

    float xv[32];
#define PLOAD(k0)                                                             \
    { _Pragma("unroll")                                                       \
      for (int i = 0; i < 32; ++i)                                            \
          xv[i] = xb[(size_t)((k0) + kB + i) * SDIM + s0 + sL]; }
#define PWRITE(b)                                                             \
    { _Pragma("unroll")                                                       \
      for (int m = 0; m < 16; ++m) {                                          \
          PK2 pk; pk.h[0] = (f16)xv[2 * m]; pk.h[1] = (f16)xv[2 * m + 1];     \
          xs[b][sL][(kB >> 1) + m] = pk.u; } }

    PLOAD(0);
    for (int ci = 0; ci < 4; ++ci) {
        const int b = ci & 1;
        PWRITE(b);
        __syncthreads();
        if (ci < 3) PLOAD((ci + 1) * 64);
        #pragma unroll
        for (int j = 0; j < 4; ++j) {
            f16x8 bx[2];
            #pragma unroll
            for (int nt = 0; nt < 2; ++nt) {
                const unsigned* pr = &xs[b][64 * wn + 32 * nt + ln][8 * j + 4 * hi];
                f16x4 lo = *(const f16x4*)pr;
                f16x4 h4 = *(const f16x4*)(pr + 2);
                f16x8 bb;
                bb[0]=lo[0]; bb[1]=lo[1]; bb[2]=lo[2]; bb[3]=lo[3];
                bb[4]=h4[0]; bb[5]=h4[1]; bb[6]=h4[2]; bb[7]=h4[3];
                bx[nt] = bb;
            }
            #pragma unroll
            for (int mt = 0; mt < 2; ++mt)
                #pragma unroll
                for (int nt = 0; nt < 2; ++nt)
                    acc[mt][nt] = __builtin_amdgcn_mfma_f32_32x32x16_f16(
                        aW[mt][ci * 4 + j], bx[nt], acc[mt][nt], 0, 0, 0);
        }
    }
#undef PLOAD
#undef PWRITE

    float bv[2][16];
    #pragma unroll
    for (int mt = 0; mt < 2; ++mt)
        #pragma unroll
        for (int r = 0; r < 16; ++r)
            bv[mt][r] = bias[m0 + 64 * wm + 32 * mt + (r & 3) + 8 * (r >> 2) + 4 * hi];

    __syncthreads();   // all compute reads of xs done before tr reuse
    if (p < 2) {
        #pragma unroll
        for (int mt = 0; mt < 2; ++mt)
            #pragma unroll
            for (int nt = 0; nt < 2; ++nt)
                #pragma unroll
                for (int r = 0; r < 16; ++r)
                    tr[64 * wn + 32 * nt + ln]
                      [64 * wm + 32 * mt + (r & 3) + 8 * (r >> 2) + 4 * hi] =
                        (f16)(acc[mt][nt][r] + bv[mt][r]);
        __syncthreads();
        f16* out = ((p == 0) ? theta_t : phi_t) + (size_t)n * SDIM * CDIM;
        const int row = t >> 1, ch = (t & 1) * 64;
        #pragma unroll
        for (int i = 0; i < 8; ++i)
            *(f16x8*)&out[(size_t)(s0 + row) * CDIM + m0 + ch + 8 * i] =
                *(const f16x8*)&tr[row][ch + 8 * i];
    } else {
        f16* out = g_out + (size_t)n * CDIM * SDIM;
        #pragma unroll
        for (int mt = 0; mt < 2; ++mt)
            #pragma unroll
            for (int nt = 0; nt < 2; ++nt)
                #pragma unroll
                for (int r = 0; r < 16; ++r)
                    out[(size_t)(m0 + 64 * wm + 32 * mt + (r & 3) + 8 * (r >> 2) + 4 * hi)
                        * SDIM + s0 + 64 * wn + 32 * nt + ln] =
                        (f16)(acc[mt][nt][r] + bv[mt][r]);
    }
}

// ---------------------------------------------------------------------------
// Kernel 2: MFMA flash attention; 4-way key split (1024 keys/block) for
// 2 blocks/CU; S^T orientation; in-register softmax; DMA staging; dbuf.
// Epilogue: per-wave LDS transpose -> Op in (s,c) f16.
// ---------------------------------------------------------------------------
__global__ __launch_bounds__(256, 2)
void attn_kernel(const f16* __restrict__ theta,
                 const f16* __restrict__ phi,
                 const f16* __restrict__ g,
                 f16* __restrict__ Op,       // [4][n][s][c] unnormalized f16
                 float* __restrict__ pm,     // [4][n][s]
                 float* __restrict__ pl)     // [4][n][s]
{
    const int bx    = blockIdx.x;
    const int n     = bx >> 5;
    const int q0    = (bx & 31) * 128;
    const int split = blockIdx.y;
    const int koff  = split * (SDIM / 4);
    const int NCH   = (SDIM / 4) / 32;      // 32 chunks of 32 keys

    __shared__ f16x8 bufP[2][1024];         // 32 KB phi
    __shared__ f16x8 bufG[2][1024];         // 32 KB G

    const int t  = threadIdx.x;
    const int w  = t >> 6;
    const int l  = t & 63;
    const int ln = l & 31;
    const int hi = l >> 5;

    const f16* thb = theta + (size_t)n * SDIM * CDIM;
    const f16* phb = phi   + (size_t)n * SDIM * CDIM;
    const f16* gb  = g     + (size_t)n * CDIM * SDIM;

    const int myq = q0 + 32 * w + ln;

    f16x8 bT[16];
    {
        const f16* ap = thb + (size_t)myq * CDIM + hi * 8;
        #pragma unroll
        for (int j = 0; j < 16; ++j)
            bT[j] = *(const f16x8*)(ap + 16 * j);
    }

    f32x16 O[8];
    #pragma unroll
    for (int ct = 0; ct < 8; ++ct)
        #pragma unroll
        for (int r = 0; r < 16; ++r) O[ct][r] = 0.0f;

    float m_run = -INFINITY, l_run = 0.0f;

#define ISSUE_CHUNK(k0, b)                                                    \
    {                                                                         \
        _Pragma("unroll")                                                     \
        for (int it = 0; it < 4; ++it) {                                      \
            const int slot = w * 256 + it * 64 + l;                           \
            const int key  = slot >> 5;                                       \
            const int grp  = (slot & 31) ^ key;                               \
            gload_lds16(phb + (size_t)((k0) + key) * CDIM + grp * 8,          \
                        &bufP[b][w * 256 + it * 64]);                         \
        }                                                                     \
        _Pragma("unroll")                                                     \
        for (int it = 0; it < 4; ++it) {                                      \
            const int slot = w * 256 + it * 64 + l;                           \
            const int kg   = slot >> 8;                                       \
            const int chan = (slot & 255) ^ (kg << 2);                        \
            gload_lds16(gb + (size_t)chan * SDIM + (k0) + kg * 8,             \
                        &bufG[b][w * 256 + it * 64]);                         \
        }                                                                     \
    }

    ISSUE_CHUNK(koff, 0);

    for (int ci = 0; ci < NCH; ++ci) {
        const int b = ci & 1;
        __syncthreads();
        if (ci + 1 < NCH) ISSUE_CHUNK(koff + (ci + 1) * 32, b ^ 1);

        // ---- S^T = phi x theta^T ----
        f32x16 sC;
        #pragma unroll
        for (int r = 0; r < 16; ++r) sC[r] = 0.0f;
        #pragma unroll
        for (int j = 0; j < 16; ++j) {
            const int grp = 2 * j + hi;
            f16x8 a = bufP[b][ln * 32 + (grp ^ ln)];
            sC = __builtin_amdgcn_mfma_f32_32x32x16_f16(a, bT[j], sC, 0, 0, 0);
        }

        // ---- in-register online softmax (lane pair holds all 32 keys) ----
        float mx = sC[0];
        #pragma unroll
        for (int r = 1; r < 16; ++r) mx = fmaxf(mx, sC[r]);
        mx = fmaxf(mx, __shfl_xor(mx, 32));
        const float mn = fmaxf(m_run, mx);
        const float al = __expf(m_run - mn);
        m_run = mn;
        float sum = 0.0f;
        #pragma unroll
        for (int r = 0; r < 16; ++r) {
            sC[r] = __expf(sC[r] - mn);
            sum += sC[r];
        }
        sum += __shfl_xor(sum, 32);
        l_run = l_run * al + sum;

        if (__any(al != 1.0f)) {
            #pragma unroll
            for (int ct = 0; ct < 8; ++ct)
                #pragma unroll
                for (int r = 0; r < 16; ++r) O[ct][r] *= al;
        }

        // ---- repack P to PV B-frags ----
        f16x8 pf[2];
        #pragma unroll
        for (int ks = 0; ks < 2; ++ks) {
            #pragma unroll
            for (int j = 0; j < 4; ++j) {
                const float own = hi ? sC[8 * ks + 4 + j] : sC[8 * ks + j];
                const float oth = hi ? sC[8 * ks + j]     : sC[8 * ks + 4 + j];
                const float par = __shfl_xor(oth, 32);
                pf[ks][j]     = (f16)(hi ? par : own);
                pf[ks][4 + j] = (f16)(hi ? own : par);
            }
        }

        // ---- PV: O^T += G x P^T ----
        #pragma unroll
        for (int ks = 0; ks < 2; ++ks) {
            const int kg = 2 * ks + hi;
            #pragma unroll
            for (int ct = 0; ct < 8; ++ct) {
                f16x8 ga = bufG[b][kg * 256 + ((32 * ct + ln) ^ (kg << 2))];
                O[ct] = __builtin_amdgcn_mfma_f32_32x32x16_f16(ga, pf[ks], O[ct], 0, 0, 0);
            }
        }
    }
#undef ISSUE_CHUNK

    // ---- epilogue: per-wave LDS transpose -> Op (s,c) f16, + (m,l) ----
    __syncthreads();   // all waves done with bufP/bufG
    {
        f16* tw = (f16*)bufP + (size_t)w * 1152;   // per-wave [32 q][36 c]
        f16* Opb = Op + ((size_t)(split * NBATCH + n)) * SDIM * CDIM;
        const int q  = l >> 1;
        const int ch = (l & 1) * 16;
        #pragma unroll
        for (int ct = 0; ct < 8; ++ct) {
            #pragma unroll
            for (int q4 = 0; q4 < 4; ++q4) {
                f16x4 v;
                v[0] = (f16)O[ct][4 * q4 + 0];
                v[1] = (f16)O[ct][4 * q4 + 1];
                v[2] = (f16)O[ct][4 * q4 + 2];
                v[3] = (f16)O[ct][4 * q4 + 3];
                *(f16x4*)&tw[ln * 36 + 8 * q4 + 4 * hi] = v;
            }
            f16x4 r0 = *(const f16x4*)&tw[q * 36 + ch + 0];
            f16x4 r1 = *(const f16x4*)&tw[q * 36 + ch + 4];
            f16x4 r2 = *(const f16x4*)&tw[q * 36 + ch + 8];
            f16x4 r3 = *(const f16x4*)&tw[q * 36 + ch + 12];
            f16x8 o0, o1;
            o0[0]=r0[0]; o0[1]=r0[1]; o0[2]=r0[2]; o0[3]=r0[3];
            o0[4]=r1[0]; o0[5]=r1[1]; o0[6]=r1[2]; o0[7]=r1[3];
            o1[0]=r2[0]; o1[1]=r2[1]; o1[2]=r2[2]; o1[3]=r2[3];
            o1[4]=r3[0]; o1[5]=r3[1]; o1[6]=r3[2]; o1[7]=r3[3];
            f16* dst = Opb + (size_t)(q0 + 32 * w + q) * CDIM + 32 * ct + ch;
            *(f16x8*)(dst)     = o0;
            *(f16x8*)(dst + 8) = o1;
        }
        if (hi == 0) {
            pm[(size_t)(split * NBATCH + n) * SDIM + myq] = m_run;
            pl[(size_t)(split * NBATCH + n) * SDIM + myq] = l_run;
        }
    }
}

// ---------------------------------------------------------------------------
// Kernel 3: MFMA output projection + residual; 4-way split combine fused
// into staging via precomputed per-s scales.
//   out[c][s] = x[c][s] + bo[c] + sum_ci Wo[c][ci] * (sum_i sc_i Op_i[s][ci])
// ---------------------------------------------------------------------------
__global__ __launch_bounds__(256, 2)
void outproj_kernel(const f16* __restrict__ Op,
                    const float* __restrict__ pm,
                    const float* __restrict__ pl,
                    const float* __restrict__ Wo,
                    const float* __restrict__ bo,
                    const float* __restrict__ x,
                    float* __restrict__ out)
{
    const int n  = blockIdx.z;
    const int s0 = blockIdx.x * 128;
    const int m0 = blockIdx.y * 128;

    __shared__ __align__(16) unsigned ys[2][128][34];
    __shared__ float scs[4][128];

    const int t = threadIdx.x, w = t >> 6, l = t & 63, ln = l & 31, hi = l >> 5;
    const int wm = w & 1, wn = w >> 1;

    if (t < 128) {
        const int s = s0 + t;
        float mv[4], lv[4];
        float M = -INFINITY;
        #pragma unroll
        for (int i = 0; i < 4; ++i) {
            mv[i] = pm[((size_t)i * NBATCH + n) * SDIM + s];
            lv[i] = pl[((size_t)i * NBATCH + n) * SDIM + s];
            M = fmaxf(M, mv[i]);
        }
        float d = 0.0f, e[4];
        #pragma unroll
        for (int i = 0; i < 4; ++i) { e[i] = __expf(mv[i] - M); d += e[i] * lv[i]; }
        const float rd = 1.0f / d;
        #pragma unroll
        for (int i = 0; i < 4; ++i) scs[i][t] = e[i] * rd;
    }

    f16x8 aW[2][16];
    #pragma unroll
    for (int mt = 0; mt < 2; ++mt) {
        const float* wr = Wo + (size_t)(m0 + 64 * wm + 32 * mt + ln) * CDIM + 8 * hi;
        #pragma unroll
        for (int j = 0; j < 16; ++j) {
            float4 u0 = *(const float4*)(wr + 16 * j);
            float4 u1 = *(const float4*)(wr + 16 * j + 4);
            f16x8 v;
            v[0] = (f16)u0.x; v[1] = (f16)u0.y; v[2] = (f16)u0.z; v[3] = (f16)u0.w;
            v[4] = (f16)u1.x; v[5] = (f16)u1.y; v[6] = (f16)u1.z; v[7] = (f16)u1.w;
            aW[mt][j] = v;
        }
    }

    f32x16 acc[2][2];
    #pragma unroll
    for (int a = 0; a < 2; ++a)
        #pragma unroll
        for (int b = 0; b < 2; ++b)
            #pragma unroll
            for (int r = 0; r < 16; ++r) acc[a][b][r] = 0.0f;

    const f16* Opb[4];
    #pragma unroll
    for (int i = 0; i < 4; ++i)
        Opb[i] = Op + ((size_t)i * NBATCH + n) * SDIM * CDIM;

    __syncthreads();   // scs ready

    f16x8 yv[4];
#define OLOAD(k0)                                                             \
    { _Pragma("unroll")                                                       \
      for (int u4 = 0; u4 < 4; ++u4) {                                        \
          const int u = u4 * 256 + t;                                         \
          const int kg = u & 7, sl = u >> 3;                                  \
          const size_t off = (size_t)(s0 + sl) * CDIM + (k0) + 8 * kg;        \
          f16x8 a0 = *(const f16x8*)(Opb[0] + off);                           \
          f16x8 a1 = *(const f16x8*)(Opb[1] + off);                           \
          f16x8 a2 = *(const f16x8*)(Opb[2] + off);                           \
          f16x8 a3 = *(const f16x8*)(Opb[3] + off);                           \
          const float c0 = scs[0][sl], c1 = scs[1][sl];                       \
          const float c2 = scs[2][sl], c3 = scs[3][sl];                       \
          f16x8 r;                                                            \
          _Pragma("unroll")                                                   \
          for (int e = 0; e < 8; ++e)                                         \
              r[e] = (f16)(c0 * (float)a0[e] + c1 * (float)a1[e] +            \
                           c2 * (float)a2[e] + c3 * (float)a3[e]);            \
          yv[u4] = r; } }
#define OWRITE(b)                                                             \
    { _Pragma("unroll")                                                       \
      for (int u4 = 0; u4 < 4; ++u4) {                                        \
          const int u = u4 * 256 + t;                                         \
          const int kg = u & 7, sl = u >> 3;                                  \
          CV8 cv; cv.v = yv[u4];                                              \
          *(uint2*)&ys[b][sl][4 * kg]     = cv.q[0];                          \
          *(uint2*)&ys[b][sl][4 * kg + 2] = cv.q[1]; } }

    OLOAD(0);
    for (int ci = 0; ci < 4; ++ci) {
        const int b = ci & 1;
        OWRITE(b);
        __syncthreads();
        if (ci < 3) OLOAD((ci + 1) * 64);
        #pragma unroll
        for (int j = 0; j < 4; ++j) {
            f16x8 bx[2];
            #pragma unroll
            for (int nt = 0; nt < 2; ++nt) {
                const unsigned* pr = &ys[b][64 * wn + 32 * nt + ln][8 * j + 4 * hi];
                f16x4 lo = *(const f16x4*)pr;
                f16x4 h4 = *(const f16x4*)(pr + 2);
                f16x8 bb;
                bb[0]=lo[0]; bb[1]=lo[1]; bb[2]=lo[2]; bb[3]=lo[3];
                bb[4]=h4[0]; bb[5]=h4[1]; bb[6]=h4[2]; bb[7]=h4[3];
                bx[nt] = bb;
            }
            #pragma unroll
            for (int mt = 0; mt < 2; ++mt)
                #pragma unroll
                for (int nt = 0; nt < 2; ++nt)
                    acc[mt][nt] = __builtin_amdgcn_mfma_f32_32x32x16_f16(
                        aW[mt][ci * 4 + j], bx[nt], acc[mt][nt], 0, 0, 0);
        }
    }
#undef OLOAD
#undef OWRITE

    const float* xb = x + (size_t)n * CDIM * SDIM;
    float* ob = out + (size_t)n * CDIM * SDIM;
    #pragma unroll
    for (int mt = 0; mt < 2; ++mt)
        #pragma unroll
        for (int r = 0; r < 16; ++r) {
            const int c = m0 + 64 * wm + 32 * mt + (r & 3) + 8 * (r >> 2) + 4 * hi;
            const float bv = bo[c];
            #pragma unroll
            for (int nt = 0; nt < 2; ++nt) {
                const size_t idx = (size_t)c * SDIM + s0 + 64 * wn + 32 * nt + ln;
                ob[idx] = acc[mt][nt][r] + bv + xb[idx];
            }
        }
}

// ---------------------------------------------------------------------------
extern "C" void kernel_launch(void* const* d_in, const int* in_sizes, int n_in,
                              void* d_out, int out_size, void* d_ws, size_t ws_size,
                              hipStream_t stream)
{
    const float* x  = (const float*)d_in[0];
    const float* Wg = (const float*)d_in[1];
    const float* bg = (const float*)d_in[2];
    const float* Wt = (const float*)d_in[3];
    const float* bt = (const float*)d_in[4];
    const float* Wp = (const float*)d_in[5];
    const float* bp = (const float*)d_in[6];
    const float* Wo = (const float*)d_in[7];
    const float* bo = (const float*)d_in[8];

    const size_t half_buf = (size_t)NBATCH * CDIM * SDIM * sizeof(f16);   // 8 MB
    const size_t mlbuf    = (size_t)4 * NBATCH * SDIM * sizeof(float);    // 256 KB
    char* wsb = (char*)d_ws;
    f16*   theta = (f16*)(wsb);
    f16*   phi   = (f16*)(wsb + half_buf);
    f16*   g     = (f16*)(wsb + 2 * half_buf);
    f16*   Op    = (f16*)(wsb + 3 * half_buf);               // 4 splits, 33.6 MB
    float* pm    = (float*)(wsb + 7 * half_buf);
    float* pl    = (float*)(wsb + 7 * half_buf + mlbuf);
    float* out   = (float*)d_out;

    proj_kernel<<<dim3(SDIM / 128, CDIM / 128, NBATCH * 3), 256, 0, stream>>>(
        x, Wt, bt, Wp, bp, Wg, bg, theta, phi, g);
    attn_kernel<<<dim3(NBATCH * (SDIM / 128), 4), 256, 0, stream>>>(
        theta, phi, g, Op, pm, pl);
    outproj_kernel<<<dim3(SDIM / 128, CDIM / 128, NBATCH), 256, 0, stream>>>(
        Op, pm, pl, Wo, bo, x, out);
}